// Round 5
// baseline (232.162 us; speedup 1.0000x reference)
//
#include <hip/hip_runtime.h>

// out = 2*tangents_1 + 99*full_default, elementwise over 104,857,600 fp32.
// HBM-bound streaming op. R4: 221 us = 5.68 TB/s demand BW = 90% of the
// 6.29 TB/s measured copy ceiling (m13). FETCH_SIZE reads exactly half of
// read demand across all structural variants -> gfx94x-formula fallback
// undercounting by 2x, i.e. NO cache absorption (working set 1.26 GB >> 288MB
// L2+L3); real HBM BW is 5.68 TB/s.
// This round: ITEMS=8 -> 16 independent 16B loads (16 KB) in flight per wave,
// chasing the last ~10% to the copy ceiling via deeper MLP.
// NOTE: __builtin_nontemporal_store needs a native clang vector type.

typedef float v4f __attribute__((ext_vector_type(4)));

constexpr int BLOCK = 256;
constexpr int ITEMS = 8;                      // v4f per thread
constexpr int CHUNK = BLOCK * ITEMS;          // 2048 v4f per block

__global__ __launch_bounds__(BLOCK) void fused_axpby_kernel(
    const v4f* __restrict__ fd,
    const v4f* __restrict__ tg,
    v4f* __restrict__ out)
{
    // 12,800 * 2048 = 26,214,400 v4f = full problem, no bounds checks needed.
    const long base = (long)blockIdx.x * CHUNK + threadIdx.x;

    v4f a[ITEMS], b[ITEMS];
#pragma unroll
    for (int k = 0; k < ITEMS; ++k) a[k] = fd[base + k * BLOCK];
#pragma unroll
    for (int k = 0; k < ITEMS; ++k) b[k] = tg[base + k * BLOCK];

    v4f r[ITEMS];
#pragma unroll
    for (int k = 0; k < ITEMS; ++k) r[k] = 2.0f * b[k] + 99.0f * a[k];

#pragma unroll
    for (int k = 0; k < ITEMS; ++k)
        __builtin_nontemporal_store(r[k], &out[base + k * BLOCK]);
}

extern "C" void kernel_launch(void* const* d_in, const int* in_sizes, int n_in,
                              void* d_out, int out_size, void* d_ws, size_t ws_size,
                              hipStream_t stream)
{
    const v4f* fd = (const v4f*)d_in[0];   // full_default
    const v4f* tg = (const v4f*)d_in[1];   // tangents_1
    v4f* out = (v4f*)d_out;

    const long n4 = (long)out_size / 4;    // 26,214,400
    const int grid = (int)(n4 / CHUNK);    // 12,800 exactly

    fused_axpby_kernel<<<grid, BLOCK, 0, stream>>>(fd, tg, out);
}

// Round 6
// 221.175 us; speedup vs baseline: 1.0497x; 1.0497x over previous
//
#include <hip/hip_runtime.h>

// out = 2*tangents_1 + 99*full_default, elementwise over 104,857,600 fp32.
// HBM-bound streaming op; traffic floor 1.258 GB (2R + 1W, fp32, no reuse).
// R4 (ITEMS=4, 25,600 blocks): 221.5 us = 5.68 TB/s = 90% of 6.29 TB/s copy
// ceiling. R5 (ITEMS=8): 232 us -- past the MLP sweet spot. This round probes
// ITEMS=2 (51,200 blocks): smoother load-balance, lower VGPR; expect null-to-
// small. If within ~3% of R4, declare roofline.
// NOTE: __builtin_nontemporal_store needs a native clang vector type.

typedef float v4f __attribute__((ext_vector_type(4)));

constexpr int BLOCK = 256;
constexpr int ITEMS = 2;                      // v4f per thread
constexpr int CHUNK = BLOCK * ITEMS;          // 512 v4f per block

__global__ __launch_bounds__(BLOCK) void fused_axpby_kernel(
    const v4f* __restrict__ fd,
    const v4f* __restrict__ tg,
    v4f* __restrict__ out)
{
    // 51,200 * 512 = 26,214,400 v4f = full problem, no bounds checks needed.
    const long base = (long)blockIdx.x * CHUNK + threadIdx.x;

    v4f a0 = fd[base + 0 * BLOCK];
    v4f a1 = fd[base + 1 * BLOCK];
    v4f b0 = tg[base + 0 * BLOCK];
    v4f b1 = tg[base + 1 * BLOCK];

    v4f r0 = 2.0f * b0 + 99.0f * a0;
    v4f r1 = 2.0f * b1 + 99.0f * a1;

    __builtin_nontemporal_store(r0, &out[base + 0 * BLOCK]);
    __builtin_nontemporal_store(r1, &out[base + 1 * BLOCK]);
}

extern "C" void kernel_launch(void* const* d_in, const int* in_sizes, int n_in,
                              void* d_out, int out_size, void* d_ws, size_t ws_size,
                              hipStream_t stream)
{
    const v4f* fd = (const v4f*)d_in[0];   // full_default
    const v4f* tg = (const v4f*)d_in[1];   // tangents_1
    v4f* out = (v4f*)d_out;

    const long n4 = (long)out_size / 4;    // 26,214,400
    const int grid = (int)(n4 / CHUNK);    // 51,200 exactly

    fused_axpby_kernel<<<grid, BLOCK, 0, stream>>>(fd, tg, out);
}